// Round 7
// baseline (556.906 us; speedup 1.0000x reference)
//
#include <hip/hip_runtime.h>
#include <hip/hip_bf16.h>
#include <cstdint>

// ---------------------------------------------------------------------------
// MultiHeadSelfAttention (B=8, S=2048, D=1024, heads=1, causal) on gfx950.
// Round 6 == round 4 (infra failures, resubmit): fused QKV projection GEMM,
// BN=256 PV GEMM, XCD swizzles.
// Pipeline: casts | QKV fused NT-GEMM | QK^T (packed triangular fp16) |
// row softmax | PV GEMM | out GEMM.
// ---------------------------------------------------------------------------

typedef short    bf16x8 __attribute__((ext_vector_type(8)));
typedef _Float16 f16x8  __attribute__((ext_vector_type(8)));
typedef _Float16 f16x4  __attribute__((ext_vector_type(4)));
typedef float    f32x4  __attribute__((ext_vector_type(4)));

#define S_LEN 2048
#define D_DIM 1024
#define M_ROWS 16384        // B*S
#define NT_Q 16             // 128-row q tiles per batch
#define SLOTS 136           // NT_Q*(NT_Q+1)/2 lower-triangle tiles
#define SLOT_ELEMS 16384    // 128*128
#define PBATCH ((size_t)SLOTS * SLOT_ELEMS)

__device__ __forceinline__ ushort f32_to_bf16_rne(float f) {
    uint32_t u = __float_as_uint(f);
    uint32_t r = (u + 0x7FFFu + ((u >> 16) & 1u)) >> 16;
    return (ushort)r;
}

__device__ __forceinline__ void gload_lds16(const void* g, void* l) {
    __builtin_amdgcn_global_load_lds(
        (const __attribute__((address_space(1))) uint32_t*)(const uint32_t*)g,
        (__attribute__((address_space(3))) uint32_t*)(uint32_t*)l, 16, 0, 0);
}

// ---------------------------------------------------------------------------
__global__ void cast_f32_bf16(const float* __restrict__ in,
                              ushort* __restrict__ out, int n4) {
    int i = blockIdx.x * blockDim.x + threadIdx.x;
    if (i < n4) {
        float4 v = ((const float4*)in)[i];
        ushort4 o;
        o.x = f32_to_bf16_rne(v.x);
        o.y = f32_to_bf16_rne(v.y);
        o.z = f32_to_bf16_rne(v.z);
        o.w = f32_to_bf16_rne(v.w);
        ((ushort4*)out)[i] = o;
    }
}

// 4 weight matrices in one launch; blockIdx.y selects the matrix.
__global__ void cast4_f32_bf16(const float* __restrict__ w0,
                               const float* __restrict__ w1,
                               const float* __restrict__ w2,
                               const float* __restrict__ w3,
                               ushort* __restrict__ o0, ushort* __restrict__ o1,
                               ushort* __restrict__ o2, ushort* __restrict__ o3,
                               int n4) {
    const int s = blockIdx.y;
    const float* in  = (s == 0) ? w0 : (s == 1) ? w1 : (s == 2) ? w2 : w3;
    ushort*      out = (s == 0) ? o0 : (s == 1) ? o1 : (s == 2) ? o2 : o3;
    int i = blockIdx.x * blockDim.x + threadIdx.x;
    if (i < n4) {
        float4 v = ((const float4*)in)[i];
        ushort4 o;
        o.x = f32_to_bf16_rne(v.x);
        o.y = f32_to_bf16_rne(v.y);
        o.z = f32_to_bf16_rne(v.z);
        o.w = f32_to_bf16_rne(v.w);
        ((ushort4*)out)[i] = o;
    }
}

// ---------------------------------------------------------------------------
// Fused QKV projection: C_w[i,j] = sum_k A[i,k]*W_w[j,k], w in {q,k,v}.
// A [16384][1024] bf16, W [1024][1024] bf16. 512 thr = 8 waves (2 wr x 4 wc),
// wave tile 64(M) x 32(N). A staged once per K-step, shared by 3 weights.
// Q,K out bf16 row-major; V out fp16 transposed per batch Vt[b][j][s].
// Grid: 1024 blocks, XCD-chunk swizzled (A-panel reuse within an XCD L2).
// ---------------------------------------------------------------------------
__global__ __launch_bounds__(512)
void gemm_qkv3(const ushort* __restrict__ A, const ushort* __restrict__ Wq,
               const ushort* __restrict__ Wk, const ushort* __restrict__ Wv,
               ushort* __restrict__ Qo, ushort* __restrict__ Ko,
               _Float16* __restrict__ Vt) {
    __shared__ ushort As[128 * 32];
    __shared__ ushort Bs[3][128 * 32];

    const int bid = blockIdx.x;
    const int g   = (bid & 7) * 128 + (bid >> 3);   // bijective: 1024 = 8*128
    const int tm  = g >> 3;                         // 0..127
    const int tn  = g & 7;                          // 0..7

    const int t  = threadIdx.x;
    const int l  = t & 63;
    const int w  = t >> 6;
    const int wr = w >> 2;          // 0..1  (64 M-rows each)
    const int wc = w & 3;           // 0..3  (32 N-cols each)
    const int lr = l & 15;
    const int lk = (l >> 4) << 3;

    f32x4 acc[3][4][2] = {};

    const int arow = t >> 2;        // 0..127
    const int acol = (t & 3) << 3;  // 0,8,16,24
    const ushort* Ag  = A  + (size_t)(tm * 128 + arow) * D_DIM + acol;
    const ushort* Bg0 = Wq + (size_t)(tn * 128 + arow) * D_DIM + acol;
    const ushort* Bg1 = Wk + (size_t)(tn * 128 + arow) * D_DIM + acol;
    const ushort* Bg2 = Wv + (size_t)(tn * 128 + arow) * D_DIM + acol;
    ushort* Al  = &As[t * 8];
    ushort* Bl0 = &Bs[0][t * 8];
    ushort* Bl1 = &Bs[1][t * 8];
    ushort* Bl2 = &Bs[2][t * 8];

    for (int k0 = 0; k0 < D_DIM; k0 += 32) {
        __syncthreads();
        gload_lds16(Ag + k0,  Al);
        gload_lds16(Bg0 + k0, Bl0);
        gload_lds16(Bg1 + k0, Bl1);
        gload_lds16(Bg2 + k0, Bl2);
        __syncthreads();

        bf16x8 af[4];
#pragma unroll
        for (int m = 0; m < 4; ++m)
            af[m] = *(const bf16x8*)&As[(wr * 64 + m * 16 + lr) * 32 + lk];
#pragma unroll
        for (int w3 = 0; w3 < 3; ++w3) {
            bf16x8 b0 = *(const bf16x8*)&Bs[w3][(wc * 32 + lr) * 32 + lk];
            bf16x8 b1 = *(const bf16x8*)&Bs[w3][(wc * 32 + 16 + lr) * 32 + lk];
#pragma unroll
            for (int m = 0; m < 4; ++m) {
                acc[w3][m][0] = __builtin_amdgcn_mfma_f32_16x16x32_bf16(
                    b0, af[m], acc[w3][m][0], 0, 0, 0);
                acc[w3][m][1] = __builtin_amdgcn_mfma_f32_16x16x32_bf16(
                    b1, af[m], acc[w3][m][1], 0, 0, 0);
            }
        }
    }

    const int cr = (l >> 4) << 2;
#pragma unroll
    for (int m = 0; m < 4; ++m) {
#pragma unroll
        for (int n = 0; n < 2; ++n) {
            const int row  = tm * 128 + wr * 64 + m * 16 + lr;
            const int col0 = tn * 128 + wc * 32 + n * 16 + cr;
            {   // Q
                f32x4 v = acc[0][m][n];
                ushort4 o;
                o.x = f32_to_bf16_rne(v[0]);
                o.y = f32_to_bf16_rne(v[1]);
                o.z = f32_to_bf16_rne(v[2]);
                o.w = f32_to_bf16_rne(v[3]);
                *(ushort4*)(Qo + (size_t)row * D_DIM + col0) = o;
            }
            {   // K
                f32x4 v = acc[1][m][n];
                ushort4 o;
                o.x = f32_to_bf16_rne(v[0]);
                o.y = f32_to_bf16_rne(v[1]);
                o.z = f32_to_bf16_rne(v[2]);
                o.w = f32_to_bf16_rne(v[3]);
                *(ushort4*)(Ko + (size_t)row * D_DIM + col0) = o;
            }
            {   // V transposed fp16
                f32x4 v = acc[2][m][n];
                const int b = row >> 11;
                const int s = row & 2047;
                size_t base = ((size_t)b * D_DIM + col0) * S_LEN + s;
#pragma unroll
                for (int r = 0; r < 4; ++r)
                    Vt[base + (size_t)r * S_LEN] = (_Float16)v[r];
            }
        }
    }
}

// ---------------------------------------------------------------------------
// QK^T over lower-triangle 128x128 tiles (packed fp16 scores), XCD-swizzled.
// ---------------------------------------------------------------------------
__global__ __launch_bounds__(256)
void gemm_qk(const ushort* __restrict__ Q, const ushort* __restrict__ K,
             _Float16* __restrict__ P) {
    __shared__ ushort As[128 * 32];
    __shared__ ushort Bs[128 * 32];

    const int b = blockIdx.y;
    const int x = blockIdx.x;
    const int s = (x & 7) * 17 + (x >> 3);   // bijective: 136 = 8*17
    int tm = (int)((sqrtf(8.0f * (float)s + 1.0f) - 1.0f) * 0.5f);
    while ((tm + 1) * (tm + 2) / 2 <= s) ++tm;
    while (tm * (tm + 1) / 2 > s) --tm;
    const int tn = s - tm * (tm + 1) / 2;

    const int t  = threadIdx.x;
    const int l  = t & 63;
    const int w  = t >> 6;
    const int wr = w >> 1, wc = w & 1;
    const int lr = l & 15;
    const int lk = (l >> 4) << 3;

    f32x4 acc[4][4] = {};

    const int arow = t >> 2;
    const int akc  = (t & 3) << 3;
    const ushort* Ag = Q + ((size_t)b * S_LEN + tm * 128 + arow) * D_DIM + akc;
    const ushort* Bg = K + ((size_t)b * S_LEN + tn * 128 + arow) * D_DIM + akc;
    ushort* Al = &As[arow * 32 + akc];
    ushort* Bl = &Bs[arow * 32 + akc];

    for (int k0 = 0; k0 < D_DIM; k0 += 32) {
        __syncthreads();
        gload_lds16(Ag + k0,              Al);
        gload_lds16(Ag + k0 + 64 * D_DIM, Al + 64 * 32);
        gload_lds16(Bg + k0,              Bl);
        gload_lds16(Bg + k0 + 64 * D_DIM, Bl + 64 * 32);
        __syncthreads();

        bf16x8 af[4], bf[4];
#pragma unroll
        for (int m = 0; m < 4; ++m)
            af[m] = *(const bf16x8*)&As[(wr * 64 + m * 16 + lr) * 32 + lk];
#pragma unroll
        for (int n = 0; n < 4; ++n)
            bf[n] = *(const bf16x8*)&Bs[(wc * 64 + n * 16 + lr) * 32 + lk];
#pragma unroll
        for (int n = 0; n < 4; ++n)
#pragma unroll
            for (int m = 0; m < 4; ++m)
                acc[n][m] = __builtin_amdgcn_mfma_f32_16x16x32_bf16(
                    bf[n], af[m], acc[n][m], 0, 0, 0);
    }

    _Float16* slot = P + (size_t)b * PBATCH + (size_t)s * SLOT_ELEMS;
    const int cr = (l >> 4) << 2;
    const float scale = 0.03125f;
#pragma unroll
    for (int n = 0; n < 4; ++n) {
#pragma unroll
        for (int m = 0; m < 4; ++m) {
            const int row_l  = wr * 64 + m * 16 + lr;
            const int col0_l = wc * 64 + n * 16 + cr;
            f32x4 v = acc[n][m];
            f16x4 o;
#pragma unroll
            for (int r = 0; r < 4; ++r) {
                float sv = v[r] * scale;
                if (tm == tn && (col0_l + r) > row_l) sv = -30000.0f;
                o[r] = (_Float16)sv;
            }
            *(f16x4*)(slot + (size_t)row_l * 128 + col0_l) = o;
        }
    }
}

// ---------------------------------------------------------------------------
// Row softmax over packed triangular scores, in place.
// ---------------------------------------------------------------------------
__global__ __launch_bounds__(256)
void softmax_rows(_Float16* __restrict__ P) {
    const int b  = blockIdx.y;
    const int q  = blockIdx.x;          // 0..2047
    const int tm = q >> 7;
    const int nchunk = (tm + 1) * 16;   // 8-elem chunks in this row
    _Float16* row = P + (size_t)b * PBATCH +
                    ((size_t)(tm * (tm + 1) / 2)) * SLOT_ELEMS +
                    (size_t)(q & 127) * 128;

    const int t = threadIdx.x;
    const bool active = t < nchunk;
    _Float16* addr = row + (size_t)(t >> 4) * SLOT_ELEMS + (t & 15) * 8;

    float v[8];
    float mx = -1e30f;
    if (active) {
        f16x8 h = *(const f16x8*)addr;
#pragma unroll
        for (int i = 0; i < 8; ++i) {
            v[i] = (float)h[i];
            mx = fmaxf(mx, v[i]);
        }
    }
#pragma unroll
    for (int d = 1; d < 64; d <<= 1) mx = fmaxf(mx, __shfl_xor(mx, d));
    __shared__ float redm[4], reds[4];
    if ((t & 63) == 0) redm[t >> 6] = mx;
    __syncthreads();
    mx = fmaxf(fmaxf(redm[0], redm[1]), fmaxf(redm[2], redm[3]));

    float sum = 0.0f;
    if (active) {
#pragma unroll
        for (int i = 0; i < 8; ++i) {
            v[i] = __expf(v[i] - mx);
            sum += v[i];
        }
    }
#pragma unroll
    for (int d = 1; d < 64; d <<= 1) sum += __shfl_xor(sum, d);
    if ((t & 63) == 0) reds[t >> 6] = sum;
    __syncthreads();
    sum = reds[0] + reds[1] + reds[2] + reds[3];
    const float inv = 1.0f / sum;

    if (active) {
        f16x8 h;
#pragma unroll
        for (int i = 0; i < 8; ++i) h[i] = (_Float16)(v[i] * inv);
        *(f16x8*)addr = h;
    }
}

// ---------------------------------------------------------------------------
// PV GEMM, BN=256: O[q][d] = sum_k P[q][k]*Vt[d][k]. 4 waves (2x2), wave
// tile 64(M) x 128(N). P staged once for 256 d-cols. K-range (tm+1)*128.
// Grid x: 64 tiles/batch, XCD-swizzled, big tm first. O bf16 row-major.
// ---------------------------------------------------------------------------
__global__ __launch_bounds__(256)
void gemm_pv2(const _Float16* __restrict__ P, const _Float16* __restrict__ Vt,
              ushort* __restrict__ O) {
    __shared__ _Float16 As[128 * 32];   // P: 128 q x 32 k
    __shared__ _Float16 Bs[256 * 32];   // Vt: 256 d x 32 k

    const int b   = blockIdx.y;
    const int x   = blockIdx.x;                 // 0..63
    const int g   = (x & 7) * 8 + (x >> 3);     // bijective: 64 = 8*8
    const int tm  = NT_Q - 1 - (g >> 2);        // big tiles first per XCD
    const int dn2 = g & 3;                      // 256-col slice
    const int KN  = (tm + 1) * 128;

    const int t  = threadIdx.x;
    const int l  = t & 63;
    const int w  = t >> 6;
    const int wr = w >> 1, wc = w & 1;
    const int lr = l & 15;
    const int lk = (l >> 4) << 3;

    f32x4 acc[4][8] = {};

    const int arow = t >> 2;        // 0..63
    const int acol = (t & 3) << 3;
    const _Float16* Prow = P + (size_t)b * PBATCH +
                           ((size_t)(tm * (tm + 1) / 2)) * SLOT_ELEMS;
    const _Float16* Vb = Vt + ((size_t)b * D_DIM + dn2 * 256 + arow) * S_LEN;
    _Float16* Al = &As[t * 8];
    _Float16* Bl = &Bs[t * 8];

    for (int k0 = 0; k0 < KN; k0 += 32) {
        const _Float16* Ag = Prow + (size_t)(k0 >> 7) * SLOT_ELEMS +
                             (size_t)arow * 128 + (k0 & 127) + acol;
        __syncthreads();
        gload_lds16(Ag,            Al);
        gload_lds16(Ag + 64 * 128, Al + 64 * 32);
        gload_lds16(Vb + k0 + acol,                 Bl);
        gload_lds16(Vb + k0 + acol + 64 * S_LEN,    Bl + 64 * 32);
        gload_lds16(Vb + k0 + acol + 128 * S_LEN,   Bl + 128 * 32);
        gload_lds16(Vb + k0 + acol + 192 * S_LEN,   Bl + 192 * 32);
        __syncthreads();

        f16x8 af[4];
#pragma unroll
        for (int m = 0; m < 4; ++m)
            af[m] = *(const f16x8*)&As[(wr * 64 + m * 16 + lr) * 32 + lk];
#pragma unroll
        for (int n = 0; n < 8; ++n) {
            f16x8 bv = *(const f16x8*)&Bs[(wc * 128 + n * 16 + lr) * 32 + lk];
#pragma unroll
            for (int m = 0; m < 4; ++m)
                acc[m][n] = __builtin_amdgcn_mfma_f32_16x16x32_f16(
                    bv, af[m], acc[m][n], 0, 0, 0);
        }
    }

    const int cr = (l >> 4) << 2;
#pragma unroll
    for (int m = 0; m < 4; ++m) {
#pragma unroll
        for (int n = 0; n < 8; ++n) {
            const int row  = tm * 128 + wr * 64 + m * 16 + lr;
            const int col0 = dn2 * 256 + wc * 128 + n * 16 + cr;
            f32x4 v = acc[m][n];
            ushort4 o;
            o.x = f32_to_bf16_rne(v[0]);
            o.y = f32_to_bf16_rne(v[1]);
            o.z = f32_to_bf16_rne(v[2]);
            o.w = f32_to_bf16_rne(v[3]);
            *(ushort4*)(O + ((size_t)b * S_LEN + row) * D_DIM + col0) = o;
        }
    }
}

// ---------------------------------------------------------------------------
// Output projection NT GEMM: C fp32 = O bf16 x Wo bf16^T. 1-D grid, XCD swz.
// ---------------------------------------------------------------------------
__global__ __launch_bounds__(256)
void gemm_out(const ushort* __restrict__ A, const ushort* __restrict__ B,
              float* __restrict__ C) {
    __shared__ ushort As[128 * 32];
    __shared__ ushort Bs[128 * 32];

    const int bid = blockIdx.x;
    const int g   = (bid & 7) * 128 + (bid >> 3);  // bijective: 1024 = 8*128
    const int tm  = g >> 3;
    const int tn  = g & 7;

    const int t  = threadIdx.x;
    const int l  = t & 63;
    const int w  = t >> 6;
    const int wr = w >> 1, wc = w & 1;
    const int lr = l & 15;
    const int lk = (l >> 4) << 3;

    f32x4 acc[4][4] = {};

    const int arow = t >> 2;
    const int akc  = (t & 3) << 3;
    const ushort* Ag = A + (size_t)(tm * 128 + arow) * D_DIM + akc;
    const ushort* Bg = B + (size_t)(tn * 128 + arow) * D_DIM + akc;
    ushort* Al = &As[arow * 32 + akc];
    ushort* Bl = &Bs[arow * 32 + akc];

    for (int k0 = 0; k0 < D_DIM; k0 += 32) {
        __syncthreads();
        gload_lds16(Ag + k0,              Al);
        gload_lds16(Ag + k0 + 64 * D_DIM, Al + 64 * 32);
        gload_lds16(Bg + k0,              Bl);
        gload_lds16(Bg + k0 + 64 * D_DIM, Bl + 64 * 32);
        __syncthreads();

        bf16x8 af[4], bf[4];
#pragma unroll
        for (int m = 0; m < 4; ++m)
            af[m] = *(const bf16x8*)&As[(wr * 64 + m * 16 + lr) * 32 + lk];
#pragma unroll
        for (int n = 0; n < 4; ++n)
            bf[n] = *(const bf16x8*)&Bs[(wc * 64 + n * 16 + lr) * 32 + lk];
#pragma unroll
        for (int n = 0; n < 4; ++n)
#pragma unroll
            for (int m = 0; m < 4; ++m)
                acc[n][m] = __builtin_amdgcn_mfma_f32_16x16x32_bf16(
                    bf[n], af[m], acc[n][m], 0, 0, 0);
    }

    const int cr = (l >> 4) << 2;
#pragma unroll
    for (int n = 0; n < 4; ++n)
#pragma unroll
        for (int m = 0; m < 4; ++m) {
            const int row  = tm * 128 + wr * 64 + m * 16 + lr;
            const int col0 = tn * 128 + wc * 64 + n * 16 + cr;
            *(f32x4*)(C + (size_t)row * D_DIM + col0) = acc[n][m];
        }
}

// ---------------------------------------------------------------------------
extern "C" void kernel_launch(void* const* d_in, const int* in_sizes, int n_in,
                              void* d_out, int out_size, void* d_ws,
                              size_t ws_size, hipStream_t stream) {
    const float* x  = (const float*)d_in[0];
    const float* Wq = (const float*)d_in[1];
    const float* Wk = (const float*)d_in[2];
    const float* Wv = (const float*)d_in[3];
    const float* Wo = (const float*)d_in[4];

    char* ws = (char*)d_ws;
    size_t off = 0;
    ushort*    xb  = (ushort*)(ws + off);    off += (size_t)M_ROWS * D_DIM * 2; // -> O
    ushort*    Wqb = (ushort*)(ws + off);    off += (size_t)D_DIM * D_DIM * 2;
    ushort*    Wkb = (ushort*)(ws + off);    off += (size_t)D_DIM * D_DIM * 2;
    ushort*    Wvb = (ushort*)(ws + off);    off += (size_t)D_DIM * D_DIM * 2;
    ushort*    Wob = (ushort*)(ws + off);    off += (size_t)D_DIM * D_DIM * 2;
    ushort*    Qb  = (ushort*)(ws + off);    off += (size_t)M_ROWS * D_DIM * 2;
    ushort*    Kb  = (ushort*)(ws + off);    off += (size_t)M_ROWS * D_DIM * 2;
    _Float16*  Vtb = (_Float16*)(ws + off);  off += (size_t)M_ROWS * D_DIM * 2;
    _Float16*  Pb  = (_Float16*)(ws + off);  off += (size_t)8 * PBATCH * 2;

    cast_f32_bf16<<<(M_ROWS * D_DIM / 4 + 255) / 256, 256, 0, stream>>>(
        x, xb, M_ROWS * D_DIM / 4);
    cast4_f32_bf16<<<dim3((D_DIM * D_DIM / 4 + 255) / 256, 4), 256, 0, stream>>>(
        Wq, Wk, Wv, Wo, Wqb, Wkb, Wvb, Wob, D_DIM * D_DIM / 4);

    gemm_qkv3<<<1024, 512, 0, stream>>>(xb, Wqb, Wkb, Wvb, Qb, Kb, Vtb);

    gemm_qk<<<dim3(SLOTS, 8), 256, 0, stream>>>(Qb, Kb, Pb);
    softmax_rows<<<dim3(S_LEN, 8), 256, 0, stream>>>(Pb);
    gemm_pv2<<<dim3(64, 8), 256, 0, stream>>>(Pb, Vtb, xb);  // O over xb

    gemm_out<<<1024, 256, 0, stream>>>(xb, Wob, (float*)d_out);
}